// Round 6
// baseline (116.362 us; speedup 1.0000x reference)
//
#include <hip/hip_runtime.h>

#define Hn 128
#define Ln 2048
#define NBn 64
#define K 64          // chunk length
#define GH 16         // chunks per block (half the sequence)
#define W 8           // waves per block
#define CPW 2         // chunks per wave
#define PITCH 68      // 64+4: rows 16B-aligned for ds_read_b128; scan writes
                      // 2-way bank aliasing (free, m136)
#define MAGICF 0x13579BDF

__device__ __forceinline__ float bcast(float v, int lane) {
    return __uint_as_float(__builtin_amdgcn_readlane(__float_as_uint(v), lane));
}

// Grid (2, Hn): blockIdx.x = sequence half, blockIdx.y = head.
// 256 blocks x 147.5 KB LDS -> exactly 1 block/CU -> all co-resident.
// w-space: w = 2*C*z (same diagonal recurrence, input coeff 2*C*B);
// y_t = sum_n Re(w_n) + D*u_t;  final z = w/(2C).
__global__ __launch_bounds__(512) void ssm_coop(
    const float* __restrict__ u,
    const float* __restrict__ x_re, const float* __restrict__ x_im,
    const float* __restrict__ Lre,  const float* __restrict__ Lim,
    const float* __restrict__ Bre,  const float* __restrict__ Bim,
    const float* __restrict__ Cre,  const float* __restrict__ Cim,
    const float* __restrict__ Dv,   const int* __restrict__ dflag,
    float* __restrict__ out,
    float2* __restrict__ Mws, int* __restrict__ flags)
{
    __shared__ float  g_s[W][K * PITCH];   // wave-private transpose buf (139 KB)
    __shared__ float2 b_s[GH][NBn];        // chunk end states (8 KB)
    __shared__ int    f_s[GH];             // chunk-has-reset flags

    const int half = blockIdx.x, h = blockIdx.y;
    const int tid = threadIdx.x, w = tid >> 6, n = tid & 63;
    const int hn = h * NBn + n;
    const int gbase = half * GH;

    const float lre = Lre[hn], lim = Lim[hn];
    const float cr  = Cre[hn], ci  = Cim[hn];
    const float br  = Bre[hn], bi  = Bim[hn];
    const float Dh  = Dv[h];
    const float cbr2 = 2.f * (cr * br - ci * bi);   // 2*C*B
    const float cbi2 = 2.f * (cr * bi + ci * br);

    float l64r = lre, l64i = lim;                   // Lam^64, 6 squarings
    #pragma unroll
    for (int it = 0; it < 6; ++it) {
        const float a  = l64r * l64r - l64i * l64i;
        const float b2 = 2.f * l64r * l64i;
        l64r = a; l64i = b2;
    }

    float ul[CPW];
    unsigned long long mk[CPW];

    // ---------- Stage A: summary-only chunk scans (s_in = 0) ----------
    #pragma unroll
    for (int j = 0; j < CPW; ++j) {
        const int gl = w * CPW + j;
        const int l0 = (gbase + gl) * K;
        ul[j] = u[h * Ln + l0 + n];
        mk[j] = __ballot(dflag[l0 + n] != 0);
        const unsigned long long m = mk[j];
        float wr = 0.f, wi = 0.f;
        if (m == 0ull) {
            #pragma unroll
            for (int k = 0; k < K; ++k) {
                const float uk = bcast(ul[j], k);
                const float nr = fmaf(lre, wr, fmaf(-lim, wi, cbr2 * uk));
                const float ni = fmaf(lre, wi, fmaf( lim, wr, cbi2 * uk));
                wr = nr; wi = ni;
            }
        } else {
            #pragma unroll
            for (int k = 0; k < K; ++k) {
                const bool  rs  = (m >> k) & 1ull;
                const float lrk = rs ? 0.f : lre;
                const float lik = rs ? 0.f : lim;
                const float uk  = bcast(ul[j], k);
                const float nr = fmaf(lrk, wr, fmaf(-lik, wi, cbr2 * uk));
                const float ni = fmaf(lrk, wi, fmaf( lik, wr, cbi2 * uk));
                wr = nr; wi = ni;
            }
        }
        b_s[gl][n] = make_float2(wr, wi);
        if (n == 0) f_s[gl] = (m != 0ull) ? 1 : 0;
    }
    __syncthreads();

    // ---------- Stage B: affine prefix over the block's 16 chunks ----------
    float Ar = 1.f, Ai = 0.f, pbr = 0.f, pbi = 0.f;
    float sAr[CPW], sAi[CPW], sbr[CPW], sbi[CPW];
    #pragma unroll
    for (int j = 0; j < GH; ++j) {
        if ((j >> 1) == w) {
            const int jj = j & 1;
            sAr[jj] = Ar; sAi[jj] = Ai; sbr[jj] = pbr; sbi[jj] = pbi;
        }
        const float2 bj = b_s[j][n];
        const bool rst = f_s[j] != 0;
        const float ajr = rst ? 0.f : l64r;
        const float aji = rst ? 0.f : l64i;
        const float nbr = fmaf(ajr, pbr, fmaf(-aji, pbi, bj.x));
        const float nbi = fmaf(ajr, pbi, fmaf( aji, pbr, bj.y));
        const float nAr = ajr * Ar - aji * Ai;
        const float nAi = ajr * Ai + aji * Ar;
        Ar = nAr; Ai = nAi; pbr = nbr; pbi = nbi;
    }
    // (Ar,Ai,pbr,pbi) = (A_16, b_16) for this block

    // ---------- Cross-block handoff of the midpoint state ----------
    float Mr, Mi;
    if (half == 0) {
        const float x0r = x_re[hn], x0i = x_im[hn];
        Mr = 2.f * (cr * x0r - ci * x0i);      // w-space initial state
        Mi = 2.f * (cr * x0i + ci * x0r);
        if (w == 0) {                          // publish midpoint
            const float mor = fmaf(Ar, Mr, fmaf(-Ai, Mi, pbr));
            const float moi = fmaf(Ar, Mi, fmaf( Ai, Mr, pbi));
            Mws[hn] = make_float2(mor, moi);
            __threadfence();
            if (n == 0)
                __hip_atomic_store(&flags[h], MAGICF, __ATOMIC_RELEASE,
                                   __HIP_MEMORY_SCOPE_AGENT);
        }
    } else {
        while (__hip_atomic_load(&flags[h], __ATOMIC_ACQUIRE,
                                 __HIP_MEMORY_SCOPE_AGENT) != MAGICF)
            __builtin_amdgcn_s_sleep(1);
        const float2 M = Mws[hn];
        Mr = M.x; Mi = M.y;
        if (w == 0) {                          // final state z = w/(2C)
            const float fr = fmaf(Ar, Mr, fmaf(-Ai, Mi, pbr));
            const float fi = fmaf(Ar, Mi, fmaf( Ai, Mr, pbi));
            const float c2r = 2.f * cr, c2i = 2.f * ci;
            const float inv = 1.f / (c2r * c2r + c2i * c2i);
            float* xlast = out + Hn * Ln;
            xlast[2 * hn + 0] = (fr * c2r + fi * c2i) * inv;
            xlast[2 * hn + 1] = (fi * c2r - fr * c2i) * inv;
        }
    }

    // ---------- Stage C: true scans from s_in, single y store ----------
    float* gbuf = g_s[w];
    #pragma unroll
    for (int j = 0; j < CPW; ++j) {
        const int gl = w * CPW + j;
        const int l0 = (gbase + gl) * K;
        float sr = fmaf(sAr[j], Mr, fmaf(-sAi[j], Mi, sbr[j]));  // s_in
        float si = fmaf(sAr[j], Mi, fmaf( sAi[j], Mr, sbi[j]));
        const unsigned long long m = mk[j];
        if (m == 0ull) {
            #pragma unroll
            for (int k = 0; k < K; ++k) {
                const float uk = bcast(ul[j], k);
                const float nr = fmaf(lre, sr, fmaf(-lim, si, cbr2 * uk));
                const float ni = fmaf(lre, si, fmaf( lim, sr, cbi2 * uk));
                sr = nr; si = ni;
                gbuf[k * PITCH + n] = sr;
            }
        } else {
            #pragma unroll
            for (int k = 0; k < K; ++k) {
                const bool  rs  = (m >> k) & 1ull;
                const float lrk = rs ? 0.f : lre;
                const float lik = rs ? 0.f : lim;
                const float uk  = bcast(ul[j], k);
                const float nr = fmaf(lrk, sr, fmaf(-lik, si, cbr2 * uk));
                const float ni = fmaf(lrk, si, fmaf( lik, sr, cbi2 * uk));
                sr = nr; si = ni;
                gbuf[k * PITCH + n] = sr;
            }
        }
        // same-wave DS in-order: no barrier needed (wave-private buffer)
        const float4* row4 = reinterpret_cast<const float4*>(gbuf + n * PITCH);
        float a0 = 0.f, a1 = 0.f, a2 = 0.f, a3 = 0.f;
        #pragma unroll
        for (int k2 = 0; k2 < K / 4; ++k2) {
            const float4 v = row4[k2];
            a0 += v.x; a1 += v.y; a2 += v.z; a3 += v.w;
        }
        out[h * Ln + l0 + n] = (a0 + a1) + (a2 + a3) + Dh * ul[j];
    }
}

extern "C" void kernel_launch(void* const* d_in, const int* in_sizes, int n_in,
                              void* d_out, int out_size, void* d_ws, size_t ws_size,
                              hipStream_t stream) {
    const float* u    = (const float*)d_in[0];
    const float* x_re = (const float*)d_in[1];
    const float* x_im = (const float*)d_in[2];
    const float* Lre  = (const float*)d_in[3];
    const float* Lim  = (const float*)d_in[4];
    const float* Bre  = (const float*)d_in[5];
    const float* Bim  = (const float*)d_in[6];
    const float* Cre  = (const float*)d_in[7];
    const float* Cim  = (const float*)d_in[8];
    const float* Dv   = (const float*)d_in[9];
    const int*   dfl  = (const int*)d_in[10];
    float* out = (float*)d_out;

    float2* Mws  = (float2*)d_ws;                 // 128*64 float2 = 64 KB
    int*    flags = (int*)((char*)d_ws + Hn * NBn * sizeof(float2));
    // ws is poisoned 0xAA by the harness before every launch -> flags start
    // at 0xAAAAAAAA != MAGICF; half-0 release-stores MAGICF after writing M.

    dim3 grid(2, Hn);
    ssm_coop<<<grid, W * 64, 0, stream>>>(u, x_re, x_im, Lre, Lim,
                                          Bre, Bim, Cre, Cim, Dv, dfl,
                                          out, Mws, flags);
}

// Round 7
// 88.654 us; speedup vs baseline: 1.3125x; 1.3125x over previous
//
#include <hip/hip_runtime.h>

#define Hn 128
#define Ln 2048
#define NBn 64
#define K 64          // chunk length
#define G 32          // chunks: G*K == Ln
#define PITCH 65      // 64+1: bank (n+k)%32 per phase -> conflict-free b32
                      // (measured 0 conflicts in R1; PITCH 68+b128 was 8-way)

// w-space: w = 2*C*z follows the same diagonal recurrence with input
// coefficient 2*C*B;  y_t = sum_n Re(w_n) + D*u_t;  final z = w/(2C).
// ws layout: Sum[(h*G+g)*NBn+n] float4 {a_re,a_im,b_re,b_im} (4 MB),
//            Sin[...] float2 {w_in_re, w_in_im}               (2 MB)

// ---------------------------------------------------------------------------
// Phase 1: per-(h,chunk) local w-space scan (s_in = 0).
//   y_local (incl. D*u) -> out;  chunk summary float4 -> Sum.
//   Reset folded into per-step Lam coeff (off the 2-fma dependent chain).
// ---------------------------------------------------------------------------
__global__ __launch_bounds__(64) void phase1_local(
    const float* __restrict__ u,
    const float* __restrict__ Lre,  const float* __restrict__ Lim,
    const float* __restrict__ Bre,  const float* __restrict__ Bim,
    const float* __restrict__ Cre,  const float* __restrict__ Cim,
    const float* __restrict__ Dv,   const int* __restrict__ dflag,
    float* __restrict__ out,
    float4* __restrict__ Sum)
{
    __shared__ float g_s[K * PITCH];
    __shared__ float u_s[K];

    const int g = blockIdx.x, h = blockIdx.y, n = threadIdx.x;
    const int hn = h * NBn + n;
    const int l0 = g * K;

    const float lre = Lre[hn], lim = Lim[hn];
    const float br  = Bre[hn], bi  = Bim[hn];
    const float cr  = Cre[hn], ci  = Cim[hn];
    const float Dh  = Dv[h];
    const float cbr2 = 2.f * (cr * br - ci * bi);   // 2*C*B
    const float cbi2 = 2.f * (cr * bi + ci * br);

    u_s[n] = u[h * Ln + l0 + n];
    const unsigned long long m = __ballot(dflag[l0 + n] != 0);
    __syncthreads();

    float wr = 0.f, wi = 0.f;
    if (m == 0ull) {                 // reset-free chunk (~53% of chunks)
        #pragma unroll
        for (int k = 0; k < K; ++k) {
            const float uk = u_s[k];               // LDS broadcast (DS pipe)
            const float nr = fmaf(lre, wr, fmaf(-lim, wi, cbr2 * uk));
            const float ni = fmaf(lre, wi, fmaf( lim, wr, cbi2 * uk));
            wr = nr; wi = ni;
            g_s[k * PITCH + n] = wr;               // only Re needed for y
        }
    } else {
        #pragma unroll
        for (int k = 0; k < K; ++k) {
            const bool  rs  = (m >> k) & 1ull;     // wave-uniform select
            const float lrk = rs ? 0.f : lre;
            const float lik = rs ? 0.f : lim;
            const float uk  = u_s[k];
            const float nr = fmaf(lrk, wr, fmaf(-lik, wi, cbr2 * uk));
            const float ni = fmaf(lrk, wi, fmaf( lik, wr, cbi2 * uk));
            wr = nr; wi = ni;
            g_s[k * PITCH + n] = wr;
        }
    }
    __syncthreads();

    // lane t sums row t (timestep l0+t): conflict-free b32 at PITCH 65
    const float* row = g_s + n * PITCH;
    float a0 = 0.f, a1 = 0.f, a2 = 0.f, a3 = 0.f;
    #pragma unroll
    for (int k = 0; k < NBn; k += 4) {
        a0 += row[k + 0]; a1 += row[k + 1];
        a2 += row[k + 2]; a3 += row[k + 3];
    }
    out[h * Ln + l0 + n] = (a0 + a1) + (a2 + a3) + Dh * u_s[n];

    // chunk summary: Lam^64 via 6 squarings, zeroed if any reset in chunk
    float pr = lre, pi = lim;
    #pragma unroll
    for (int it = 0; it < 6; ++it) {
        const float sr2 = pr * pr - pi * pi;
        const float si2 = 2.f * pr * pi;
        pr = sr2; pi = si2;
    }
    if (m) { pr = 0.f; pi = 0.f; }
    Sum[(h * G + g) * NBn + n] = make_float4(pr, pi, wr, wi);
}

// ---------------------------------------------------------------------------
// Phase 2: per-head serial combine in w-space (one dwordx4 per chunk, fully
// unrolled so loads pipeline ahead of the 8-cyc FMA chain); writes each
// chunk's incoming w-state to Sin; final z = w/(2C) -> out.
// ---------------------------------------------------------------------------
__global__ __launch_bounds__(64) void phase2_combine(
    const float* __restrict__ x_re, const float* __restrict__ x_im,
    const float* __restrict__ Cre,  const float* __restrict__ Cim,
    const float4* __restrict__ Sum,
    float2* __restrict__ Sin,
    float* __restrict__ out)
{
    const int h = blockIdx.x, n = threadIdx.x;
    const int hn = h * NBn + n;
    const float cr = Cre[hn], ci = Cim[hn];
    const float x0r = x_re[hn], x0i = x_im[hn];
    float sre = 2.f * (cr * x0r - ci * x0i);    // w-space initial state
    float sim = 2.f * (cr * x0i + ci * x0r);
    #pragma unroll
    for (int g = 0; g < G; ++g) {
        const int idx = (h * G + g) * NBn + n;
        const float4 s = Sum[idx];
        Sin[idx] = make_float2(sre, sim);
        const float nr = fmaf(s.x, sre, fmaf(-s.y, sim, s.z));
        const float ni = fmaf(s.x, sim, fmaf( s.y, sre, s.w));
        sre = nr; sim = ni;
    }
    const float c2r = 2.f * cr, c2i = 2.f * ci; // z = w/(2C)
    const float inv = 1.f / (c2r * c2r + c2i * c2i);
    float* xlast = out + Hn * Ln;
    xlast[2 * hn + 0] = (sre * c2r + sim * c2i) * inv;
    xlast[2 * hn + 1] = (sim * c2r - sre * c2i) * inv;
}

// ---------------------------------------------------------------------------
// Phase 3: per-(h,chunk) correction  y[l0+k] += sum_n Re(Lam_n^{k+1} w_in_n)
// (w-space: no C multiply), masked from the first reset onward. Lam-power
// chain split into two interleaved Lam^2 chains (half the dependent depth).
// ---------------------------------------------------------------------------
__global__ __launch_bounds__(64) void phase3_fixup(
    const float* __restrict__ Lre, const float* __restrict__ Lim,
    const int* __restrict__ dflag,
    const float2* __restrict__ Sin,
    float* __restrict__ out)
{
    __shared__ float g_s[K * PITCH];

    const int g = blockIdx.x, h = blockIdx.y, n = threadIdx.x;
    const int hn = h * NBn + n;
    const int l0 = g * K;

    const float2 s = Sin[(h * G + g) * NBn + n];   // w_in
    const float lre = Lre[hn], lim = Lim[hn];

    const unsigned long long bal = __ballot(dflag[l0 + n] != 0);
    const int kr = bal ? (__ffsll((long long)bal) - 1) : K;

    const float l2r = lre * lre - lim * lim;       // Lam^2
    const float l2i = 2.f * lre * lim;

    float tAr = fmaf(lre, s.x, -lim * s.y);        // k=0: w_in*Lam
    float tAi = fmaf(lre, s.y,  lim * s.x);
    float tBr = fmaf(l2r, s.x, -l2i * s.y);        // k=1: w_in*Lam^2
    float tBi = fmaf(l2r, s.y,  l2i * s.x);
    g_s[0 * PITCH + n] = tAr;
    g_s[1 * PITCH + n] = tBr;
    #pragma unroll
    for (int k = 2; k < K; k += 2) {
        const float nAr = fmaf(l2r, tAr, -l2i * tAi);
        const float nAi = fmaf(l2r, tAi,  l2i * tAr);
        tAr = nAr; tAi = nAi;
        g_s[k * PITCH + n] = tAr;
        const float nBr = fmaf(l2r, tBr, -l2i * tBi);
        const float nBi = fmaf(l2r, tBi,  l2i * tBr);
        tBr = nBr; tBi = nBi;
        g_s[(k + 1) * PITCH + n] = tBr;
    }
    __syncthreads();

    const float* row = g_s + n * PITCH;
    float a0 = 0.f, a1 = 0.f, a2 = 0.f, a3 = 0.f;
    #pragma unroll
    for (int k = 0; k < NBn; k += 4) {
        a0 += row[k + 0]; a1 += row[k + 1];
        a2 += row[k + 2]; a3 += row[k + 3];
    }
    if (n < kr)
        out[h * Ln + l0 + n] += (a0 + a1) + (a2 + a3);
}

extern "C" void kernel_launch(void* const* d_in, const int* in_sizes, int n_in,
                              void* d_out, int out_size, void* d_ws, size_t ws_size,
                              hipStream_t stream) {
    const float* u    = (const float*)d_in[0];
    const float* x_re = (const float*)d_in[1];
    const float* x_im = (const float*)d_in[2];
    const float* Lre  = (const float*)d_in[3];
    const float* Lim  = (const float*)d_in[4];
    const float* Bre  = (const float*)d_in[5];
    const float* Bim  = (const float*)d_in[6];
    const float* Cre  = (const float*)d_in[7];
    const float* Cim  = (const float*)d_in[8];
    const float* Dv   = (const float*)d_in[9];
    const int*   dfl  = (const int*)d_in[10];
    float* out = (float*)d_out;

    const int HGN = Hn * G * NBn;          // 262144 entries
    float4* Sum = (float4*)d_ws;           // 4 MB
    float2* Sin = (float2*)(Sum + HGN);    // 2 MB

    dim3 grid(G, Hn);
    phase1_local<<<grid, 64, 0, stream>>>(u, Lre, Lim, Bre, Bim, Cre, Cim,
                                          Dv, dfl, out, Sum);
    phase2_combine<<<Hn, 64, 0, stream>>>(x_re, x_im, Cre, Cim, Sum, Sin, out);
    phase3_fixup<<<grid, 64, 0, stream>>>(Lre, Lim, dfl, Sin, out);
}